// Round 8
// baseline (328.746 us; speedup 1.0000x reference)
//
#include <hip/hip_runtime.h>

typedef __attribute__((ext_vector_type(8))) short s8v;
typedef __attribute__((ext_vector_type(4))) short s4v;
typedef __attribute__((ext_vector_type(4))) float f4v;

#define MFMA16(a, b, c) __builtin_amdgcn_mfma_f32_16x16x32_bf16((a), (b), (c), 0, 0, 0)
#define AS1 __attribute__((address_space(1)))
#define AS3 __attribute__((address_space(3)))

__device__ __forceinline__ short f2bf(float f) {  // RNE
  union { float f; unsigned u; } v; v.f = f;
  unsigned r = v.u + 0x7FFFu + ((v.u >> 16) & 1u);
  return (short)(r >> 16);
}
__device__ __forceinline__ float bf2f(short s) {
  union { unsigned u; float f; } v; v.u = ((unsigned)(unsigned short)s) << 16;
  return v.f;
}
__device__ __forceinline__ unsigned fbits(float f) {
  union { float f; unsigned u; } v; v.f = f; return v.u;
}
// pack two f32 -> dword of two bf16 (truncate)
__device__ __forceinline__ unsigned pack2(float hi, float lo) {
  return __builtin_amdgcn_perm(fbits(hi), fbits(lo), 0x07060302u);
}
// pack two f32 -> dword of two bf16 (round-half-up)
__device__ __forceinline__ unsigned pack2rn(float hi, float lo) {
  return __builtin_amdgcn_perm(fbits(hi) + 0x8000u, fbits(lo) + 0x8000u, 0x07060302u);
}
__device__ __forceinline__ void gld16(const void* g, void* l) {
  __builtin_amdgcn_global_load_lds((const AS1 unsigned*)g, (AS3 unsigned*)l, 16, 0, 0);
}

// ---------- merged prep: weight transpose+cast AND input cast, one launch ----
// blocks [0,1024): weight transpose; z = b>>8 selects W, 16x16 tile grid.
// blocks [1024,7168): input cast; c = b-1024, y = c>>11 selects Q/K/V stream.
__global__ __launch_bounds__(256) void prep(
    const float* __restrict__ W0, const float* __restrict__ W1,
    const float* __restrict__ W2, const float* __restrict__ W3,
    short* __restrict__ Wt,
    const float* __restrict__ A0, const float* __restrict__ A1,
    const float* __restrict__ A2, short* __restrict__ Ac) {
  __shared__ float tile[64][65];
  const int b = blockIdx.x, t = threadIdx.x;
  if (b < 1024) {
    const int z = b >> 8, xy = b & 255, bx = xy & 15, by = xy >> 4;
    const float* W = z == 0 ? W0 : z == 1 ? W1 : z == 2 ? W2 : W3;
    short* Wtz = Wt + (size_t)z * 1048576;
    const int r0 = by * 64, c0 = bx * 64;
    for (int i = 0; i < 4; ++i) {
      int lin = t + i * 256;
      int row = lin >> 4, c4 = (lin & 15) << 2;
      float4 v = *(const float4*)(W + (size_t)(r0 + row) * 1024 + c0 + c4);
      tile[row][c4 + 0] = v.x; tile[row][c4 + 1] = v.y;
      tile[row][c4 + 2] = v.z; tile[row][c4 + 3] = v.w;
    }
    __syncthreads();
    for (int i = 0; i < 4; ++i) {
      int lin = t + i * 256;
      int nl = lin >> 4, k4 = (lin & 15) << 2;
      s4v sv = { f2bf(tile[k4 + 0][nl]), f2bf(tile[k4 + 1][nl]),
                 f2bf(tile[k4 + 2][nl]), f2bf(tile[k4 + 3][nl]) };
      *(s4v*)&Wtz[(size_t)(c0 + nl) * 1024 + r0 + k4] = sv;
    }
  } else {
    const int c = b - 1024;
    const int y = c >> 11, x = c & 2047;
    const float* A = y == 0 ? A0 : y == 1 ? A1 : A2;
    short* o = Ac + (size_t)y * 8388608;
    const size_t base = ((size_t)x * 256 + t) * 16;
    const float4 v0 = *(const float4*)(A + base);
    const float4 v1 = *(const float4*)(A + base + 4);
    const float4 v2 = *(const float4*)(A + base + 8);
    const float4 v3 = *(const float4*)(A + base + 12);
    union { s8v v; unsigned u[4]; } p0, p1;
    p0.u[0] = pack2rn(v0.y, v0.x); p0.u[1] = pack2rn(v0.w, v0.z);
    p0.u[2] = pack2rn(v1.y, v1.x); p0.u[3] = pack2rn(v1.w, v1.z);
    p1.u[0] = pack2rn(v2.y, v2.x); p1.u[1] = pack2rn(v2.w, v2.z);
    p1.u[2] = pack2rn(v3.y, v3.x); p1.u[3] = pack2rn(v3.w, v3.z);
    *(s8v*)(o + base) = p0.v;
    *(s8v*)(o + base + 8) = p1.v;
  }
}

// ---------- 2-phase GEMM (T2+T3+T4+T5): BM=128 BN=256 BK=64, 512 thr ----------
// LDS: 3 K-tile buffers x (A 8192 + B 16384 shorts) = 144 KB.
// Swizzle (T2): logical [row][64 bf16] byte L at physical P = L ^ ((row&7)<<4).
// Staged via global_load_lds with linear dest + inverse-swizzled global source;
// ds_read side applies the swizzle -> conflict-free (verified: conflicts 20x down).
// Loads issued 2 K-tiles ahead; s_waitcnt vmcnt(6) per tile boundary (T4).
// 2 phases per K-tile, 16 MFMA per phase (m201 density): phase A = m01 x n0123,
// phase B = m23 x n0123. MFMA operands SWAPPED (mfma(b,a)): acc rows = feats.
#define GLDA(j, bb, kt) gld16(Asrc[j] + (size_t)(kt) * 64, &smem[(bb) + ldsA + (j) * 4096])
#define GLDB(j, bb, kt) gld16(Bsrc[j] + (size_t)(kt) * 64, &smem[(bb) + 8192 + ldsA + (j) * 4096])

template <int EPI>
__global__ __launch_bounds__(512, 2) void gemm8p(
    const short* __restrict__ Ab, const short* __restrict__ Bt,
    const float* __restrict__ b0, const float* __restrict__ b1,
    const float* __restrict__ b2, float s0,
    short* __restrict__ outb) {
  __shared__ __align__(16) short smem[73728];   // 147456 B

  const int z = blockIdx.z;
  Ab += (size_t)z * 8388608;
  Bt += (size_t)z * 1048576;
  outb += (size_t)z * 8388608;
  const float* bias = z == 0 ? b0 : z == 1 ? b1 : b2;
  const float scale = z == 0 ? s0 : 1.f;

  const int tid = threadIdx.x;
  const int lane = tid & 63, w = tid >> 6;
  const int quad = lane >> 4, l16 = lane & 15;
  const int wm = (w >> 2) * 64, wn = (w & 3) * 64;   // 2M x 4N waves, 64x64 each
  const int mBase = blockIdx.x * 128, nBase = blockIdx.y * 256;

  f4v acc[4][4] = {};   // acc[nt][mt]: feat-frag nt, token-frag mt

  // staging: thread covers linear LDS slot s -> logical row s>>3,
  // logical col shorts ((s&7)^((s>>3)&7))<<3  (inverse swizzle on source)
  const short* Asrc[2];
  const short* Bsrc[4];
#pragma unroll
  for (int j = 0; j < 2; ++j) {
    int s = tid + j * 512;
    Asrc[j] = Ab + (size_t)(mBase + (s >> 3)) * 1024 + (((s & 7) ^ ((s >> 3) & 7)) << 3);
  }
#pragma unroll
  for (int j = 0; j < 4; ++j) {
    int s = tid + j * 512;
    Bsrc[j] = Bt + (size_t)(nBase + (s >> 3)) * 1024 + (((s & 7) ^ ((s >> 3) & 7)) << 3);
  }
  const int ldsA = tid * 8;

  // fragment read offsets (shorts within buf): row*64 + ((kh*4+quad)^(l16&7))<<3
  int axk[2];
#pragma unroll
  for (int kh = 0; kh < 2; ++kh) axk[kh] = (((kh * 4 + quad) ^ (l16 & 7)) << 3);
  const int arow = (wm + l16) * 64;          // + mt*1024
  const int brow = 8192 + (wn + l16) * 64;   // + nt*1024

  // ---- prologue: stage tiles 0,1,2 into bufs 0,1,2 (6 loads each) ----
#pragma unroll
  for (int t = 0; t < 3; ++t) {
    const int bb = t * 24576;
    GLDB(0, bb, t); GLDB(1, bb, t); GLDB(2, bb, t); GLDB(3, bb, t);
    GLDA(0, bb, t); GLDA(1, bb, t);
  }
  asm volatile("s_waitcnt vmcnt(12)" ::: "memory");   // tile 0 resident
  __builtin_amdgcn_s_barrier();

  int cb = 0, sb = 49152;   // current buf, stage buf (tile kt+2)
#pragma unroll 1
  for (int kt = 0; kt < 16; ++kt) {
    const bool st = (kt + 2) < 16;
    s8v a[4][2], b[4][2];
    // ---- phase A: frags b0123,a01 | stage B0-3(t+2) | MFMA m01 x n0123 ----
#pragma unroll
    for (int kh = 0; kh < 2; ++kh) {
      b[0][kh] = *(const s8v*)&smem[cb + brow + 0 * 1024 + axk[kh]];
      b[1][kh] = *(const s8v*)&smem[cb + brow + 1 * 1024 + axk[kh]];
      b[2][kh] = *(const s8v*)&smem[cb + brow + 2 * 1024 + axk[kh]];
      b[3][kh] = *(const s8v*)&smem[cb + brow + 3 * 1024 + axk[kh]];
      a[0][kh] = *(const s8v*)&smem[cb + arow + 0 * 1024 + axk[kh]];
      a[1][kh] = *(const s8v*)&smem[cb + arow + 1 * 1024 + axk[kh]];
    }
    if (st) { GLDB(0, sb, kt + 2); GLDB(1, sb, kt + 2); GLDB(2, sb, kt + 2); GLDB(3, sb, kt + 2); }
    __builtin_amdgcn_s_barrier();
    __builtin_amdgcn_s_setprio(1);
#pragma unroll
    for (int nt = 0; nt < 4; ++nt)
#pragma unroll
      for (int mt = 0; mt < 2; ++mt)
#pragma unroll
        for (int kh = 0; kh < 2; ++kh)
          acc[nt][mt] = MFMA16(b[nt][kh], a[mt][kh], acc[nt][mt]);
    __builtin_amdgcn_s_setprio(0);
    __builtin_amdgcn_s_barrier();
    // ---- phase B: frags a23 | stage A0,A1(t+2) | MFMA m23 x n0123 ----
#pragma unroll
    for (int kh = 0; kh < 2; ++kh) {
      a[2][kh] = *(const s8v*)&smem[cb + arow + 2 * 1024 + axk[kh]];
      a[3][kh] = *(const s8v*)&smem[cb + arow + 3 * 1024 + axk[kh]];
    }
    if (st) { GLDA(0, sb, kt + 2); GLDA(1, sb, kt + 2); }
    __builtin_amdgcn_s_barrier();
    __builtin_amdgcn_s_setprio(1);
#pragma unroll
    for (int nt = 0; nt < 4; ++nt)
#pragma unroll
      for (int mt = 2; mt < 4; ++mt)
#pragma unroll
        for (int kh = 0; kh < 2; ++kh)
          acc[nt][mt] = MFMA16(b[nt][kh], a[mt][kh], acc[nt][mt]);
    __builtin_amdgcn_s_setprio(0);
    // ---- tile boundary: counted vmcnt (never 0 in steady state) ----
    if (kt < 14) {
      asm volatile("s_waitcnt vmcnt(6)" ::: "memory");   // next tile resident
    } else if (kt == 14) {
      asm volatile("s_waitcnt vmcnt(0)" ::: "memory");   // tail drain
    }
    if (kt < 15) __builtin_amdgcn_s_barrier();
    cb = (cb == 49152) ? 0 : cb + 24576;
    sb = (sb == 49152) ? 0 : sb + 24576;
  }

  // ---- epilogue: LDS transpose (pool is dead), coalesced 16B stores ----
  f4v bv_[4];
#pragma unroll
  for (int nt = 0; nt < 4; ++nt)
    bv_[nt] = *(const f4v*)&bias[nBase + wn + nt * 16 + quad * 4];

  const int bI = mBase >> 11, tok0 = mBase & 2047;
  const bool vpath = (EPI == 0) && (z == 2);
  if (vpath) {
    short (*Tv)[136] = (short(*)[136])smem;   // [feat 256][tok 128]
#pragma unroll
    for (int nt = 0; nt < 4; ++nt)
#pragma unroll
      for (int r = 0; r < 4; ++r) {
        int feat = wn + nt * 16 + quad * 4 + r;
#pragma unroll
        for (int mt = 0; mt < 4; ++mt)
          Tv[feat][wm + mt * 16 + l16] = f2bf(acc[nt][mt][r] + bv_[nt][r]);
      }
    __syncthreads();
#pragma unroll
    for (int it = 0; it < 8; ++it) {
      int id = tid + it * 512;
      int f = id >> 4, t8 = (id & 15) << 3;
      s8v v = *(const s8v*)&Tv[f][t8];
      int gf = nBase + f, h = gf >> 6, d = gf & 63;
      *(s8v*)&outb[(((size_t)bI * 16 + h) * 64 + d) * 2048 + tok0 + t8] = v;
    }
  } else {
    short (*Ta)[264] = (short(*)[264])smem;   // [tok 128][feat 256]
#pragma unroll
    for (int nt = 0; nt < 4; ++nt)
#pragma unroll
      for (int mt = 0; mt < 4; ++mt) {
        union { s4v v; unsigned u[2]; } pk;
        pk.u[0] = pack2rn((acc[nt][mt][1] + bv_[nt][1]) * scale,
                          (acc[nt][mt][0] + bv_[nt][0]) * scale);
        pk.u[1] = pack2rn((acc[nt][mt][3] + bv_[nt][3]) * scale,
                          (acc[nt][mt][2] + bv_[nt][2]) * scale);
        *(s4v*)&Ta[wm + mt * 16 + l16][wn + nt * 16 + quad * 4] = pk.v;
      }
    __syncthreads();
#pragma unroll
    for (int it = 0; it < 8; ++it) {
      int id = tid + it * 512;
      int tok = id >> 5, f8 = (id & 31) << 3;
      s8v v = *(const s8v*)&Ta[tok][f8];
      if constexpr (EPI == 1) {
        *(s8v*)&outb[(size_t)(mBase + tok) * 1024 + nBase + f8] = v;
      } else {
        int gf = nBase + f8, h = gf >> 6, d = gf & 63;
        *(s8v*)&outb[(((size_t)bI * 16 + h) * 2048 + tok0 + tok) * 64 + d] = v;
      }
    }
  }
}

// ---------- flash attention: r3 structure + T14 issue-early staging + T5 ----
// 256 thr = 4 waves x 64 q-rows; grid (qt=8, bh=64) = 512 blocks, 2/CU.
// T14 fix: kn/vn global loads are issued AFTER __syncthreads + ds_reads (not
// before the barrier, where syncthreads' implicit s_waitcnt vmcnt(0) drained
// them at full L2/HBM latency every kv with all waves locked). Loads now fly
// across the whole MFMA/exp/PV phase; the auto vmcnt wait lands at the
// loop-bottom LDS write, after ~2000 cycles of cover.
// setprio(1) around the La/PV MFMA cluster (T5, +4-7% attn per m191).
// T1 XCD swizzle: XCD x owns bh in [8x,8x+8) -> per-XCD K/V set = 4 MB = L2.
__global__ __launch_bounds__(256, 2) void attn_kernel(
    const short* __restrict__ Qp, const short* __restrict__ Kp,
    const short* __restrict__ Vpt, short* __restrict__ Ctx) {
  __shared__ __align__(16) short Ks[2][64][72];
  __shared__ __align__(16) short Vt[2][64][72];

  const int tid = threadIdx.x, w = tid >> 6, lane = tid & 63;
  const int quad = lane >> 4, l16 = lane & 15;
  const int lin = blockIdx.x + (blockIdx.y << 3);
  const int xcd = lin & 7, j = lin >> 3;
  const int bh = (xcd << 3) | (j >> 3), qt = j & 7;
  const short* Qb = Qp + (size_t)bh * 2048 * 64;
  const short* Kb = Kp + (size_t)bh * 2048 * 64;
  const short* Vb = Vpt + (size_t)bh * 64 * 2048;
  const int qbase = qt * 256 + w * 64;

  int sg[2], sc8[2], sp[2];
  const short* Ksrc[2];
  const short* Vsrc[2];
#pragma unroll
  for (int i = 0; i < 2; ++i) {
    int id = tid + i * 256;
    int g = id >> 3, c8 = (id & 7) << 3;
    int p = (g & 32) | (((g >> 2) & 1) << 4) | (((g >> 3) & 3) << 2) | (g & 3);
    sg[i] = g; sc8[i] = c8; sp[i] = p;
    Ksrc[i] = Kb + (size_t)g * 64 + c8;
    Vsrc[i] = Vb + (size_t)g * 2048 + c8;
  }

  s8v qf[4][2];
#pragma unroll
  for (int mt = 0; mt < 4; ++mt)
#pragma unroll
    for (int h = 0; h < 2; ++h)
      qf[mt][h] = *(const s8v*)(Qb + (size_t)(qbase + mt * 16 + l16) * 64 + h * 32 + quad * 8);

  {
    s8v kr[2], vr[2];
#pragma unroll
    for (int i = 0; i < 2; ++i) { kr[i] = *(const s8v*)Ksrc[i]; vr[i] = *(const s8v*)Vsrc[i]; }
#pragma unroll
    for (int i = 0; i < 2; ++i) {
      *(s8v*)&Ks[0][sp[i]][sc8[i]] = kr[i];
      *(s8v*)&Vt[0][sg[i]][sc8[i]] = vr[i];
    }
  }

  const s8v vone = {16256, 16256, 16256, 16256, 16256, 16256, 16256, 16256};
  f4v Oa[4][4] = {};
  f4v La[4] = {};

  for (int kv = 0; kv < 32; ++kv) {
    const int buf = kv & 1;
    __syncthreads();   // buf's staging writes (prev iter) visible; vm queue empty

    s8v kf[4][2], vf[4][2];
#pragma unroll
    for (int T = 0; T < 4; ++T) {
      kf[T][0] = *(const s8v*)&Ks[buf][T * 16 + l16][quad * 8];
      kf[T][1] = *(const s8v*)&Ks[buf][T * 16 + l16][32 + quad * 8];
      vf[T][0] = *(const s8v*)&Vt[buf][T * 16 + l16][quad * 8];
      vf[T][1] = *(const s8v*)&Vt[buf][T * 16 + l16][32 + quad * 8];
    }

    // T14: issue next-tile global loads now; latency hides under compute below
    s8v kn[2], vn[2];
    if (kv < 31) {
#pragma unroll
      for (int i = 0; i < 2; ++i) {
        kn[i] = *(const s8v*)(Ksrc[i] + (size_t)(kv + 1) * 4096);
        vn[i] = *(const s8v*)(Vsrc[i] + (size_t)(kv + 1) * 64);
      }
    }

#pragma unroll
    for (int mt = 0; mt < 4; ++mt) {
      f4v s[4] = {};
#pragma unroll
      for (int T = 0; T < 4; ++T) {
        s[T] = MFMA16(kf[T][0], qf[mt][0], s[T]);
        s[T] = MFMA16(kf[T][1], qf[mt][1], s[T]);
      }
#pragma unroll
      for (int T = 0; T < 4; ++T)
#pragma unroll
        for (int r = 0; r < 4; ++r)
          s[T][r] = __builtin_amdgcn_exp2f(s[T][r]);
      s8v pf[2];
#pragma unroll
      for (int cp = 0; cp < 2; ++cp) {
        union { s8v v; unsigned u[4]; } pk;
        pk.u[0] = pack2(s[2 * cp][1], s[2 * cp][0]);
        pk.u[1] = pack2(s[2 * cp][3], s[2 * cp][2]);
        pk.u[2] = pack2(s[2 * cp + 1][1], s[2 * cp + 1][0]);
        pk.u[3] = pack2(s[2 * cp + 1][3], s[2 * cp + 1][2]);
        pf[cp] = pk.v;
      }
      __builtin_amdgcn_s_setprio(1);
      La[mt] = MFMA16(pf[0], vone, La[mt]);
      La[mt] = MFMA16(pf[1], vone, La[mt]);
#pragma unroll
      for (int nt = 0; nt < 4; ++nt) {
        Oa[mt][nt] = MFMA16(pf[0], vf[nt][0], Oa[mt][nt]);
        Oa[mt][nt] = MFMA16(pf[1], vf[nt][1], Oa[mt][nt]);
      }
      __builtin_amdgcn_s_setprio(0);
    }

    if (kv < 31) {
#pragma unroll
      for (int i = 0; i < 2; ++i) {
        *(s8v*)&Ks[buf ^ 1][sp[i]][sc8[i]] = kn[i];
        *(s8v*)&Vt[buf ^ 1][sg[i]][sc8[i]] = vn[i];
      }
    }
  }

  const int b = bh >> 4, h = bh & 15;
#pragma unroll
  for (int mt = 0; mt < 4; ++mt)
#pragma unroll
    for (int r = 0; r < 4; ++r) {
      float inv = 1.f / La[mt][r];
      int q = qbase + mt * 16 + quad * 4 + r;
#pragma unroll
      for (int nt = 0; nt < 4; ++nt) {
        int d = nt * 16 + l16;
        Ctx[((size_t)b * 2048 + q) * 1024 + h * 64 + d] = f2bf(Oa[mt][nt][r] * inv);
      }
    }
}

// ---------- residual + LayerNorm (attn input in bf16) ----------
__global__ __launch_bounds__(256) void ln_kernel(
    const float* __restrict__ resid, const short* __restrict__ attnb,
    const float* __restrict__ gamma, const float* __restrict__ beta,
    float* __restrict__ out) {
  const int row = blockIdx.x, t = threadIdx.x;
  const float4 rv = *(const float4*)(resid + (size_t)row * 1024 + t * 4);
  const s4v av = *(const s4v*)(attnb + (size_t)row * 1024 + t * 4);
  float x0 = rv.x + bf2f(av[0]), x1 = rv.y + bf2f(av[1]);
  float x2 = rv.z + bf2f(av[2]), x3 = rv.w + bf2f(av[3]);
  float s = x0 + x1 + x2 + x3;
  float ss = x0 * x0 + x1 * x1 + x2 * x2 + x3 * x3;
  for (int off = 32; off > 0; off >>= 1) {
    s += __shfl_down(s, off, 64);
    ss += __shfl_down(ss, off, 64);
  }
  __shared__ float red[8];
  const int wid = t >> 6, lane = t & 63;
  if (lane == 0) { red[wid] = s; red[4 + wid] = ss; }
  __syncthreads();
  float S = red[0] + red[1] + red[2] + red[3];
  float SS = red[4] + red[5] + red[6] + red[7];
  float mu = S * (1.f / 1024.f);
  float var = SS * (1.f / 1024.f) - mu * mu;
  float rstd = rsqrtf(var + 1e-5f);
  const float4 g = *(const float4*)(gamma + t * 4);
  const float4 bb = *(const float4*)(beta + t * 4);
  float4 o;
  o.x = (x0 - mu) * rstd * g.x + bb.x;
  o.y = (x1 - mu) * rstd * g.y + bb.y;
  o.z = (x2 - mu) * rstd * g.z + bb.z;
  o.w = (x3 - mu) * rstd * g.w + bb.w;
  *(float4*)(out + (size_t)row * 1024 + t * 4) = o;
}

extern "C" void kernel_launch(void* const* d_in, const int* in_sizes, int n_in,
                              void* d_out, int out_size, void* d_ws, size_t ws_size,
                              hipStream_t stream) {
  const float* Qin = (const float*)d_in[0];
  const float* Kin = (const float*)d_in[1];
  const float* Vin = (const float*)d_in[2];
  const float* Wq = (const float*)d_in[3];
  const float* bq = (const float*)d_in[4];
  const float* Wk = (const float*)d_in[5];
  const float* bk = (const float*)d_in[6];
  const float* Wv = (const float*)d_in[7];
  const float* bv = (const float*)d_in[8];
  const float* Wo = (const float*)d_in[9];
  const float* bo = (const float*)d_in[10];
  const float* gamma = (const float*)d_in[11];
  const float* beta = (const float*)d_in[12];
  float* out = (float*)d_out;

  char* ws = (char*)d_ws;
  const size_t MB = 1024 * 1024;
  // Layout (peak 104 MB):
  //  [0,48M)   Qp/Kp/Vpt  (QKV gemm out; live through attn)
  //  [48,96M)  Acast      (bf16 inputs; dead after QKV gemm)  -> reused:
  //  [48,64M)  Ctx        (attn out)
  //  [64,80M)  AOutB      (O-proj out)
  //  [96,104M) Wt         (4 x 2MB transposed weights)
  short* Qp    = (short*)(ws);
  short* Acast = (short*)(ws + 48 * MB);
  short* Ctx   = (short*)(ws + 48 * MB);
  short* AOutB = (short*)(ws + 64 * MB);
  short* Wt    = (short*)(ws + 96 * MB);

  prep<<<7168, 256, 0, stream>>>(Wq, Wk, Wv, Wo, Wt, Qin, Kin, Vin, Acast);

  const float qscale = 0.125f * 1.44269504f;  // 1/sqrt(64) * log2(e)

  gemm8p<0><<<dim3(64, 4, 3), 512, 0, stream>>>(
      Acast, Wt, bq, bk, bv, qscale, Qp);

  attn_kernel<<<dim3(8, 64), 256, 0, stream>>>(Qp, Qp + 8388608, Qp + 16777216, Ctx);

  gemm8p<1><<<dim3(64, 4, 1), 512, 0, stream>>>(
      Ctx, Wt + 3 * 1048576, bo, bo, bo, 1.f, AOutB);

  ln_kernel<<<8192, 256, 0, stream>>>(Qin, AOutB, gamma, beta, out);
}

// Round 9
// 318.380 us; speedup vs baseline: 1.0326x; 1.0326x over previous
//
#include <hip/hip_runtime.h>

typedef __attribute__((ext_vector_type(8))) short s8v;
typedef __attribute__((ext_vector_type(4))) short s4v;
typedef __attribute__((ext_vector_type(4))) float f4v;

#define MFMA16(a, b, c) __builtin_amdgcn_mfma_f32_16x16x32_bf16((a), (b), (c), 0, 0, 0)
#define AS1 __attribute__((address_space(1)))
#define AS3 __attribute__((address_space(3)))

__device__ __forceinline__ short f2bf(float f) {  // RNE
  union { float f; unsigned u; } v; v.f = f;
  unsigned r = v.u + 0x7FFFu + ((v.u >> 16) & 1u);
  return (short)(r >> 16);
}
__device__ __forceinline__ float bf2f(short s) {
  union { unsigned u; float f; } v; v.u = ((unsigned)(unsigned short)s) << 16;
  return v.f;
}
__device__ __forceinline__ unsigned fbits(float f) {
  union { float f; unsigned u; } v; v.f = f; return v.u;
}
// pack two f32 -> dword of two bf16 (truncate)
__device__ __forceinline__ unsigned pack2(float hi, float lo) {
  return __builtin_amdgcn_perm(fbits(hi), fbits(lo), 0x07060302u);
}
// pack two f32 -> dword of two bf16 (round-half-up)
__device__ __forceinline__ unsigned pack2rn(float hi, float lo) {
  return __builtin_amdgcn_perm(fbits(hi) + 0x8000u, fbits(lo) + 0x8000u, 0x07060302u);
}
__device__ __forceinline__ void gld16(const void* g, void* l) {
  __builtin_amdgcn_global_load_lds((const AS1 unsigned*)g, (AS3 unsigned*)l, 16, 0, 0);
}

// ---------- merged prep: weight transpose+cast AND input cast, one launch ----
// blocks [0,1024): weight transpose; z = b>>8 selects W, 16x16 tile grid.
// blocks [1024,7168): input cast; c = b-1024, y = c>>11 selects Q/K/V stream.
__global__ __launch_bounds__(256) void prep(
    const float* __restrict__ W0, const float* __restrict__ W1,
    const float* __restrict__ W2, const float* __restrict__ W3,
    short* __restrict__ Wt,
    const float* __restrict__ A0, const float* __restrict__ A1,
    const float* __restrict__ A2, short* __restrict__ Ac) {
  __shared__ float tile[64][65];
  const int b = blockIdx.x, t = threadIdx.x;
  if (b < 1024) {
    const int z = b >> 8, xy = b & 255, bx = xy & 15, by = xy >> 4;
    const float* W = z == 0 ? W0 : z == 1 ? W1 : z == 2 ? W2 : W3;
    short* Wtz = Wt + (size_t)z * 1048576;
    const int r0 = by * 64, c0 = bx * 64;
    for (int i = 0; i < 4; ++i) {
      int lin = t + i * 256;
      int row = lin >> 4, c4 = (lin & 15) << 2;
      float4 v = *(const float4*)(W + (size_t)(r0 + row) * 1024 + c0 + c4);
      tile[row][c4 + 0] = v.x; tile[row][c4 + 1] = v.y;
      tile[row][c4 + 2] = v.z; tile[row][c4 + 3] = v.w;
    }
    __syncthreads();
    for (int i = 0; i < 4; ++i) {
      int lin = t + i * 256;
      int nl = lin >> 4, k4 = (lin & 15) << 2;
      s4v sv = { f2bf(tile[k4 + 0][nl]), f2bf(tile[k4 + 1][nl]),
                 f2bf(tile[k4 + 2][nl]), f2bf(tile[k4 + 3][nl]) };
      *(s4v*)&Wtz[(size_t)(c0 + nl) * 1024 + r0 + k4] = sv;
    }
  } else {
    const int c = b - 1024;
    const int y = c >> 11, x = c & 2047;
    const float* A = y == 0 ? A0 : y == 1 ? A1 : A2;
    short* o = Ac + (size_t)y * 8388608;
    const size_t base = ((size_t)x * 256 + t) * 16;
    const float4 v0 = *(const float4*)(A + base);
    const float4 v1 = *(const float4*)(A + base + 4);
    const float4 v2 = *(const float4*)(A + base + 8);
    const float4 v3 = *(const float4*)(A + base + 12);
    union { s8v v; unsigned u[4]; } p0, p1;
    p0.u[0] = pack2rn(v0.y, v0.x); p0.u[1] = pack2rn(v0.w, v0.z);
    p0.u[2] = pack2rn(v1.y, v1.x); p0.u[3] = pack2rn(v1.w, v1.z);
    p1.u[0] = pack2rn(v2.y, v2.x); p1.u[1] = pack2rn(v2.w, v2.z);
    p1.u[2] = pack2rn(v3.y, v3.x); p1.u[3] = pack2rn(v3.w, v3.z);
    *(s8v*)(o + base) = p0.v;
    *(s8v*)(o + base + 8) = p1.v;
  }
}

// ---------- 2-phase GEMM (T2+T3+T4+T5): BM=128 BN=256 BK=64, 512 thr ----------
// LDS: 3 K-tile buffers x (A 8192 + B 16384 shorts) = 144 KB.
// Swizzle (T2): logical [row][64 bf16] byte L at physical P = L ^ ((row&7)<<4).
// Staged via global_load_lds with linear dest + inverse-swizzled global source;
// ds_read side applies the swizzle -> conflict-free (verified: conflicts 20x down).
// Loads issued 2 K-tiles ahead; s_waitcnt vmcnt(6) per tile boundary (T4).
// 2 phases per K-tile, 16 MFMA per phase (m201 density): phase A = m01 x n0123,
// phase B = m23 x n0123. MFMA operands SWAPPED (mfma(b,a)): acc rows = feats.
#define GLDA(j, bb, kt) gld16(Asrc[j] + (size_t)(kt) * 64, &smem[(bb) + ldsA + (j) * 4096])
#define GLDB(j, bb, kt) gld16(Bsrc[j] + (size_t)(kt) * 64, &smem[(bb) + 8192 + ldsA + (j) * 4096])

template <int EPI>
__global__ __launch_bounds__(512, 2) void gemm8p(
    const short* __restrict__ Ab, const short* __restrict__ Bt,
    const float* __restrict__ b0, const float* __restrict__ b1,
    const float* __restrict__ b2, float s0,
    short* __restrict__ outb) {
  __shared__ __align__(16) short smem[73728];   // 147456 B

  const int z = blockIdx.z;
  Ab += (size_t)z * 8388608;
  Bt += (size_t)z * 1048576;
  outb += (size_t)z * 8388608;
  const float* bias = z == 0 ? b0 : z == 1 ? b1 : b2;
  const float scale = z == 0 ? s0 : 1.f;

  const int tid = threadIdx.x;
  const int lane = tid & 63, w = tid >> 6;
  const int quad = lane >> 4, l16 = lane & 15;
  const int wm = (w >> 2) * 64, wn = (w & 3) * 64;   // 2M x 4N waves, 64x64 each
  const int mBase = blockIdx.x * 128, nBase = blockIdx.y * 256;

  f4v acc[4][4] = {};   // acc[nt][mt]: feat-frag nt, token-frag mt

  // staging: thread covers linear LDS slot s -> logical row s>>3,
  // logical col shorts ((s&7)^((s>>3)&7))<<3  (inverse swizzle on source)
  const short* Asrc[2];
  const short* Bsrc[4];
#pragma unroll
  for (int j = 0; j < 2; ++j) {
    int s = tid + j * 512;
    Asrc[j] = Ab + (size_t)(mBase + (s >> 3)) * 1024 + (((s & 7) ^ ((s >> 3) & 7)) << 3);
  }
#pragma unroll
  for (int j = 0; j < 4; ++j) {
    int s = tid + j * 512;
    Bsrc[j] = Bt + (size_t)(nBase + (s >> 3)) * 1024 + (((s & 7) ^ ((s >> 3) & 7)) << 3);
  }
  const int ldsA = tid * 8;

  // fragment read offsets (shorts within buf): row*64 + ((kh*4+quad)^(l16&7))<<3
  int axk[2];
#pragma unroll
  for (int kh = 0; kh < 2; ++kh) axk[kh] = (((kh * 4 + quad) ^ (l16 & 7)) << 3);
  const int arow = (wm + l16) * 64;          // + mt*1024
  const int brow = 8192 + (wn + l16) * 64;   // + nt*1024

  // ---- prologue: stage tiles 0,1,2 into bufs 0,1,2 (6 loads each) ----
#pragma unroll
  for (int t = 0; t < 3; ++t) {
    const int bb = t * 24576;
    GLDB(0, bb, t); GLDB(1, bb, t); GLDB(2, bb, t); GLDB(3, bb, t);
    GLDA(0, bb, t); GLDA(1, bb, t);
  }
  asm volatile("s_waitcnt vmcnt(12)" ::: "memory");   // tile 0 resident
  __builtin_amdgcn_s_barrier();

  int cb = 0, sb = 49152;   // current buf, stage buf (tile kt+2)
#pragma unroll 1
  for (int kt = 0; kt < 16; ++kt) {
    const bool st = (kt + 2) < 16;
    s8v a[4][2], b[4][2];
    // ---- phase A: frags b0123,a01 | stage B0-3(t+2) | MFMA m01 x n0123 ----
#pragma unroll
    for (int kh = 0; kh < 2; ++kh) {
      b[0][kh] = *(const s8v*)&smem[cb + brow + 0 * 1024 + axk[kh]];
      b[1][kh] = *(const s8v*)&smem[cb + brow + 1 * 1024 + axk[kh]];
      b[2][kh] = *(const s8v*)&smem[cb + brow + 2 * 1024 + axk[kh]];
      b[3][kh] = *(const s8v*)&smem[cb + brow + 3 * 1024 + axk[kh]];
      a[0][kh] = *(const s8v*)&smem[cb + arow + 0 * 1024 + axk[kh]];
      a[1][kh] = *(const s8v*)&smem[cb + arow + 1 * 1024 + axk[kh]];
    }
    if (st) { GLDB(0, sb, kt + 2); GLDB(1, sb, kt + 2); GLDB(2, sb, kt + 2); GLDB(3, sb, kt + 2); }
    __builtin_amdgcn_s_barrier();
    __builtin_amdgcn_s_setprio(1);
#pragma unroll
    for (int nt = 0; nt < 4; ++nt)
#pragma unroll
      for (int mt = 0; mt < 2; ++mt)
#pragma unroll
        for (int kh = 0; kh < 2; ++kh)
          acc[nt][mt] = MFMA16(b[nt][kh], a[mt][kh], acc[nt][mt]);
    __builtin_amdgcn_s_setprio(0);
    __builtin_amdgcn_s_barrier();
    // ---- phase B: frags a23 | stage A0,A1(t+2) | MFMA m23 x n0123 ----
#pragma unroll
    for (int kh = 0; kh < 2; ++kh) {
      a[2][kh] = *(const s8v*)&smem[cb + arow + 2 * 1024 + axk[kh]];
      a[3][kh] = *(const s8v*)&smem[cb + arow + 3 * 1024 + axk[kh]];
    }
    if (st) { GLDA(0, sb, kt + 2); GLDA(1, sb, kt + 2); }
    __builtin_amdgcn_s_barrier();
    __builtin_amdgcn_s_setprio(1);
#pragma unroll
    for (int nt = 0; nt < 4; ++nt)
#pragma unroll
      for (int mt = 2; mt < 4; ++mt)
#pragma unroll
        for (int kh = 0; kh < 2; ++kh)
          acc[nt][mt] = MFMA16(b[nt][kh], a[mt][kh], acc[nt][mt]);
    __builtin_amdgcn_s_setprio(0);
    // ---- tile boundary: counted vmcnt (never 0 in steady state) ----
    if (kt < 14) {
      asm volatile("s_waitcnt vmcnt(6)" ::: "memory");   // next tile resident
    } else if (kt == 14) {
      asm volatile("s_waitcnt vmcnt(0)" ::: "memory");   // tail drain
    }
    if (kt < 15) __builtin_amdgcn_s_barrier();
    cb = (cb == 49152) ? 0 : cb + 24576;
    sb = (sb == 49152) ? 0 : sb + 24576;
  }

  // ---- epilogue: LDS transpose (pool is dead), coalesced 16B stores ----
  f4v bv_[4];
#pragma unroll
  for (int nt = 0; nt < 4; ++nt)
    bv_[nt] = *(const f4v*)&bias[nBase + wn + nt * 16 + quad * 4];

  const int bI = mBase >> 11, tok0 = mBase & 2047;
  const bool vpath = (EPI == 0) && (z == 2);
  if (vpath) {
    short (*Tv)[136] = (short(*)[136])smem;   // [feat 256][tok 128]
#pragma unroll
    for (int nt = 0; nt < 4; ++nt)
#pragma unroll
      for (int r = 0; r < 4; ++r) {
        int feat = wn + nt * 16 + quad * 4 + r;
#pragma unroll
        for (int mt = 0; mt < 4; ++mt)
          Tv[feat][wm + mt * 16 + l16] = f2bf(acc[nt][mt][r] + bv_[nt][r]);
      }
    __syncthreads();
#pragma unroll
    for (int it = 0; it < 8; ++it) {
      int id = tid + it * 512;
      int f = id >> 4, t8 = (id & 15) << 3;
      s8v v = *(const s8v*)&Tv[f][t8];
      int gf = nBase + f, h = gf >> 6, d = gf & 63;
      *(s8v*)&outb[(((size_t)bI * 16 + h) * 64 + d) * 2048 + tok0 + t8] = v;
    }
  } else {
    short (*Ta)[264] = (short(*)[264])smem;   // [tok 128][feat 256]
#pragma unroll
    for (int nt = 0; nt < 4; ++nt)
#pragma unroll
      for (int mt = 0; mt < 4; ++mt) {
        union { s4v v; unsigned u[2]; } pk;
        pk.u[0] = pack2rn((acc[nt][mt][1] + bv_[nt][1]) * scale,
                          (acc[nt][mt][0] + bv_[nt][0]) * scale);
        pk.u[1] = pack2rn((acc[nt][mt][3] + bv_[nt][3]) * scale,
                          (acc[nt][mt][2] + bv_[nt][2]) * scale);
        *(s4v*)&Ta[wm + mt * 16 + l16][wn + nt * 16 + quad * 4] = pk.v;
      }
    __syncthreads();
#pragma unroll
    for (int it = 0; it < 8; ++it) {
      int id = tid + it * 512;
      int tok = id >> 5, f8 = (id & 31) << 3;
      s8v v = *(const s8v*)&Ta[tok][f8];
      if constexpr (EPI == 1) {
        *(s8v*)&outb[(size_t)(mBase + tok) * 1024 + nBase + f8] = v;
      } else {
        int gf = nBase + f8, h = gf >> 6, d = gf & 63;
        *(s8v*)&outb[(((size_t)bI * 16 + h) * 2048 + tok0 + tok) * 64 + d] = v;
      }
    }
  }
}

// ---------- flash attention: S^T scheme, P in registers, dbuf K/V staging ----
// EXACT round-3 inner loop (measured 71.2 us twice) -- all structural variants
// (kv-split occupancy r6, SW-pipeline r7, issue-late T14 r8) measured worse.
// Loads for kv+1 issue at loop TOP; the barrier's implicit vmcnt(0) drain
// overlaps other waves' barrier arrival. No setprio (r3 form).
// T1 XCD swizzle: XCD x owns bh in [8x,8x+8) -> per-XCD K/V set = 4 MB = L2.
__global__ __launch_bounds__(256, 2) void attn_kernel(
    const short* __restrict__ Qp, const short* __restrict__ Kp,
    const short* __restrict__ Vpt, short* __restrict__ Ctx) {
  __shared__ __align__(16) short Ks[2][64][72];
  __shared__ __align__(16) short Vt[2][64][72];

  const int tid = threadIdx.x, w = tid >> 6, lane = tid & 63;
  const int quad = lane >> 4, l16 = lane & 15;
  const int lin = blockIdx.x + (blockIdx.y << 3);
  const int xcd = lin & 7, j = lin >> 3;
  const int bh = (xcd << 3) | (j >> 3), qt = j & 7;
  const short* Qb = Qp + (size_t)bh * 2048 * 64;
  const short* Kb = Kp + (size_t)bh * 2048 * 64;
  const short* Vb = Vpt + (size_t)bh * 64 * 2048;
  const int qbase = qt * 256 + w * 64;

  int sg[2], sc8[2], sp[2];
  const short* Ksrc[2];
  const short* Vsrc[2];
#pragma unroll
  for (int i = 0; i < 2; ++i) {
    int id = tid + i * 256;
    int g = id >> 3, c8 = (id & 7) << 3;
    int p = (g & 32) | (((g >> 2) & 1) << 4) | (((g >> 3) & 3) << 2) | (g & 3);
    sg[i] = g; sc8[i] = c8; sp[i] = p;
    Ksrc[i] = Kb + (size_t)g * 64 + c8;
    Vsrc[i] = Vb + (size_t)g * 2048 + c8;
  }

  s8v qf[4][2];
#pragma unroll
  for (int mt = 0; mt < 4; ++mt)
#pragma unroll
    for (int h = 0; h < 2; ++h)
      qf[mt][h] = *(const s8v*)(Qb + (size_t)(qbase + mt * 16 + l16) * 64 + h * 32 + quad * 8);

  {
    s8v kr[2], vr[2];
#pragma unroll
    for (int i = 0; i < 2; ++i) { kr[i] = *(const s8v*)Ksrc[i]; vr[i] = *(const s8v*)Vsrc[i]; }
#pragma unroll
    for (int i = 0; i < 2; ++i) {
      *(s8v*)&Ks[0][sp[i]][sc8[i]] = kr[i];
      *(s8v*)&Vt[0][sg[i]][sc8[i]] = vr[i];
    }
  }

  const s8v vone = {16256, 16256, 16256, 16256, 16256, 16256, 16256, 16256};
  f4v Oa[4][4] = {};
  f4v La[4] = {};

  for (int kv = 0; kv < 32; ++kv) {
    const int buf = kv & 1;
    s8v kn[2], vn[2];
    if (kv < 31) {
#pragma unroll
      for (int i = 0; i < 2; ++i) {
        kn[i] = *(const s8v*)(Ksrc[i] + (size_t)(kv + 1) * 4096);
        vn[i] = *(const s8v*)(Vsrc[i] + (size_t)(kv + 1) * 64);
      }
    }
    __syncthreads();   // buf's staging writes (prev iter) visible

    s8v kf[4][2], vf[4][2];
#pragma unroll
    for (int T = 0; T < 4; ++T) {
      kf[T][0] = *(const s8v*)&Ks[buf][T * 16 + l16][quad * 8];
      kf[T][1] = *(const s8v*)&Ks[buf][T * 16 + l16][32 + quad * 8];
      vf[T][0] = *(const s8v*)&Vt[buf][T * 16 + l16][quad * 8];
      vf[T][1] = *(const s8v*)&Vt[buf][T * 16 + l16][32 + quad * 8];
    }

#pragma unroll
    for (int mt = 0; mt < 4; ++mt) {
      f4v s[4] = {};
#pragma unroll
      for (int T = 0; T < 4; ++T) {
        s[T] = MFMA16(kf[T][0], qf[mt][0], s[T]);
        s[T] = MFMA16(kf[T][1], qf[mt][1], s[T]);
      }
#pragma unroll
      for (int T = 0; T < 4; ++T)
#pragma unroll
        for (int r = 0; r < 4; ++r)
          s[T][r] = __builtin_amdgcn_exp2f(s[T][r]);
      s8v pf[2];
#pragma unroll
      for (int cp = 0; cp < 2; ++cp) {
        union { s8v v; unsigned u[4]; } pk;
        pk.u[0] = pack2(s[2 * cp][1], s[2 * cp][0]);
        pk.u[1] = pack2(s[2 * cp][3], s[2 * cp][2]);
        pk.u[2] = pack2(s[2 * cp + 1][1], s[2 * cp + 1][0]);
        pk.u[3] = pack2(s[2 * cp + 1][3], s[2 * cp + 1][2]);
        pf[cp] = pk.v;
      }
      La[mt] = MFMA16(pf[0], vone, La[mt]);
      La[mt] = MFMA16(pf[1], vone, La[mt]);
#pragma unroll
      for (int nt = 0; nt < 4; ++nt) {
        Oa[mt][nt] = MFMA16(pf[0], vf[nt][0], Oa[mt][nt]);
        Oa[mt][nt] = MFMA16(pf[1], vf[nt][1], Oa[mt][nt]);
      }
    }

    if (kv < 31) {
#pragma unroll
      for (int i = 0; i < 2; ++i) {
        *(s8v*)&Ks[buf ^ 1][sp[i]][sc8[i]] = kn[i];
        *(s8v*)&Vt[buf ^ 1][sg[i]][sc8[i]] = vn[i];
      }
    }
  }

  const int b = bh >> 4, h = bh & 15;
#pragma unroll
  for (int mt = 0; mt < 4; ++mt)
#pragma unroll
    for (int r = 0; r < 4; ++r) {
      float inv = 1.f / La[mt][r];
      int q = qbase + mt * 16 + quad * 4 + r;
#pragma unroll
      for (int nt = 0; nt < 4; ++nt) {
        int d = nt * 16 + l16;
        Ctx[((size_t)b * 2048 + q) * 1024 + h * 64 + d] = f2bf(Oa[mt][nt][r] * inv);
      }
    }
}

// ---------- residual + LayerNorm (attn input in bf16) ----------
__global__ __launch_bounds__(256) void ln_kernel(
    const float* __restrict__ resid, const short* __restrict__ attnb,
    const float* __restrict__ gamma, const float* __restrict__ beta,
    float* __restrict__ out) {
  const int row = blockIdx.x, t = threadIdx.x;
  const float4 rv = *(const float4*)(resid + (size_t)row * 1024 + t * 4);
  const s4v av = *(const s4v*)(attnb + (size_t)row * 1024 + t * 4);
  float x0 = rv.x + bf2f(av[0]), x1 = rv.y + bf2f(av[1]);
  float x2 = rv.z + bf2f(av[2]), x3 = rv.w + bf2f(av[3]);
  float s = x0 + x1 + x2 + x3;
  float ss = x0 * x0 + x1 * x1 + x2 * x2 + x3 * x3;
  for (int off = 32; off > 0; off >>= 1) {
    s += __shfl_down(s, off, 64);
    ss += __shfl_down(ss, off, 64);
  }
  __shared__ float red[8];
  const int wid = t >> 6, lane = t & 63;
  if (lane == 0) { red[wid] = s; red[4 + wid] = ss; }
  __syncthreads();
  float S = red[0] + red[1] + red[2] + red[3];
  float SS = red[4] + red[5] + red[6] + red[7];
  float mu = S * (1.f / 1024.f);
  float var = SS * (1.f / 1024.f) - mu * mu;
  float rstd = rsqrtf(var + 1e-5f);
  const float4 g = *(const float4*)(gamma + t * 4);
  const float4 bb = *(const float4*)(beta + t * 4);
  float4 o;
  o.x = (x0 - mu) * rstd * g.x + bb.x;
  o.y = (x1 - mu) * rstd * g.y + bb.y;
  o.z = (x2 - mu) * rstd * g.z + bb.z;
  o.w = (x3 - mu) * rstd * g.w + bb.w;
  *(float4*)(out + (size_t)row * 1024 + t * 4) = o;
}

extern "C" void kernel_launch(void* const* d_in, const int* in_sizes, int n_in,
                              void* d_out, int out_size, void* d_ws, size_t ws_size,
                              hipStream_t stream) {
  const float* Qin = (const float*)d_in[0];
  const float* Kin = (const float*)d_in[1];
  const float* Vin = (const float*)d_in[2];
  const float* Wq = (const float*)d_in[3];
  const float* bq = (const float*)d_in[4];
  const float* Wk = (const float*)d_in[5];
  const float* bk = (const float*)d_in[6];
  const float* Wv = (const float*)d_in[7];
  const float* bv = (const float*)d_in[8];
  const float* Wo = (const float*)d_in[9];
  const float* bo = (const float*)d_in[10];
  const float* gamma = (const float*)d_in[11];
  const float* beta = (const float*)d_in[12];
  float* out = (float*)d_out;

  char* ws = (char*)d_ws;
  const size_t MB = 1024 * 1024;
  // Layout (peak 104 MB):
  //  [0,48M)   Qp/Kp/Vpt  (QKV gemm out; live through attn)
  //  [48,96M)  Acast      (bf16 inputs; dead after QKV gemm)  -> reused:
  //  [48,64M)  Ctx        (attn out)
  //  [64,80M)  AOutB      (O-proj out)
  //  [96,104M) Wt         (4 x 2MB transposed weights)
  short* Qp    = (short*)(ws);
  short* Acast = (short*)(ws + 48 * MB);
  short* Ctx   = (short*)(ws + 48 * MB);
  short* AOutB = (short*)(ws + 64 * MB);
  short* Wt    = (short*)(ws + 96 * MB);

  prep<<<7168, 256, 0, stream>>>(Wq, Wk, Wv, Wo, Wt, Qin, Kin, Vin, Acast);

  const float qscale = 0.125f * 1.44269504f;  // 1/sqrt(64) * log2(e)

  gemm8p<0><<<dim3(64, 4, 3), 512, 0, stream>>>(
      Acast, Wt, bq, bk, bv, qscale, Qp);

  attn_kernel<<<dim3(8, 64), 256, 0, stream>>>(Qp, Qp + 8388608, Qp + 16777216, Ctx);

  gemm8p<1><<<dim3(64, 4, 1), 512, 0, stream>>>(
      Ctx, Wt + 3 * 1048576, bo, bo, bo, 1.f, AOutB);

  ln_kernel<<<8192, 256, 0, stream>>>(Qin, AOutB, gamma, beta, out);
}

// Round 10
// 315.083 us; speedup vs baseline: 1.0434x; 1.0105x over previous
//
#include <hip/hip_runtime.h>

typedef __attribute__((ext_vector_type(8))) short s8v;
typedef __attribute__((ext_vector_type(4))) short s4v;
typedef __attribute__((ext_vector_type(4))) float f4v;

#define MFMA16(a, b, c) __builtin_amdgcn_mfma_f32_16x16x32_bf16((a), (b), (c), 0, 0, 0)
#define AS1 __attribute__((address_space(1)))
#define AS3 __attribute__((address_space(3)))

__device__ __forceinline__ short f2bf(float f) {  // RNE
  union { float f; unsigned u; } v; v.f = f;
  unsigned r = v.u + 0x7FFFu + ((v.u >> 16) & 1u);
  return (short)(r >> 16);
}
__device__ __forceinline__ float bf2f(short s) {
  union { unsigned u; float f; } v; v.u = ((unsigned)(unsigned short)s) << 16;
  return v.f;
}
__device__ __forceinline__ unsigned fbits(float f) {
  union { float f; unsigned u; } v; v.f = f; return v.u;
}
// pack two f32 -> dword of two bf16 (truncate)
__device__ __forceinline__ unsigned pack2(float hi, float lo) {
  return __builtin_amdgcn_perm(fbits(hi), fbits(lo), 0x07060302u);
}
// pack two f32 -> dword of two bf16 (round-half-up)
__device__ __forceinline__ unsigned pack2rn(float hi, float lo) {
  return __builtin_amdgcn_perm(fbits(hi) + 0x8000u, fbits(lo) + 0x8000u, 0x07060302u);
}
__device__ __forceinline__ void gld16(const void* g, void* l) {
  __builtin_amdgcn_global_load_lds((const AS1 unsigned*)g, (AS3 unsigned*)l, 16, 0, 0);
}

// ---------- merged prep: weight transpose+cast AND input cast, one launch ----
// blocks [0,1024): weight transpose; z = b>>8 selects W, 16x16 tile grid.
// blocks [1024,7168): input cast; c = b-1024, y = c>>11 selects Q/K/V stream.
__global__ __launch_bounds__(256) void prep(
    const float* __restrict__ W0, const float* __restrict__ W1,
    const float* __restrict__ W2, const float* __restrict__ W3,
    short* __restrict__ Wt,
    const float* __restrict__ A0, const float* __restrict__ A1,
    const float* __restrict__ A2, short* __restrict__ Ac) {
  __shared__ float tile[64][65];
  const int b = blockIdx.x, t = threadIdx.x;
  if (b < 1024) {
    const int z = b >> 8, xy = b & 255, bx = xy & 15, by = xy >> 4;
    const float* W = z == 0 ? W0 : z == 1 ? W1 : z == 2 ? W2 : W3;
    short* Wtz = Wt + (size_t)z * 1048576;
    const int r0 = by * 64, c0 = bx * 64;
    for (int i = 0; i < 4; ++i) {
      int lin = t + i * 256;
      int row = lin >> 4, c4 = (lin & 15) << 2;
      float4 v = *(const float4*)(W + (size_t)(r0 + row) * 1024 + c0 + c4);
      tile[row][c4 + 0] = v.x; tile[row][c4 + 1] = v.y;
      tile[row][c4 + 2] = v.z; tile[row][c4 + 3] = v.w;
    }
    __syncthreads();
    for (int i = 0; i < 4; ++i) {
      int lin = t + i * 256;
      int nl = lin >> 4, k4 = (lin & 15) << 2;
      s4v sv = { f2bf(tile[k4 + 0][nl]), f2bf(tile[k4 + 1][nl]),
                 f2bf(tile[k4 + 2][nl]), f2bf(tile[k4 + 3][nl]) };
      *(s4v*)&Wtz[(size_t)(c0 + nl) * 1024 + r0 + k4] = sv;
    }
  } else {
    const int c = b - 1024;
    const int y = c >> 11, x = c & 2047;
    const float* A = y == 0 ? A0 : y == 1 ? A1 : A2;
    short* o = Ac + (size_t)y * 8388608;
    const size_t base = ((size_t)x * 256 + t) * 16;
    const float4 v0 = *(const float4*)(A + base);
    const float4 v1 = *(const float4*)(A + base + 4);
    const float4 v2 = *(const float4*)(A + base + 8);
    const float4 v3 = *(const float4*)(A + base + 12);
    union { s8v v; unsigned u[4]; } p0, p1;
    p0.u[0] = pack2rn(v0.y, v0.x); p0.u[1] = pack2rn(v0.w, v0.z);
    p0.u[2] = pack2rn(v1.y, v1.x); p0.u[3] = pack2rn(v1.w, v1.z);
    p1.u[0] = pack2rn(v2.y, v2.x); p1.u[1] = pack2rn(v2.w, v2.z);
    p1.u[2] = pack2rn(v3.y, v3.x); p1.u[3] = pack2rn(v3.w, v3.z);
    *(s8v*)(o + base) = p0.v;
    *(s8v*)(o + base + 8) = p1.v;
  }
}

// ---------- 1-phase GEMM (T2+T4): BM=128 BN=256 BK=64, 512 thr ----------
// LDS: 3 K-tile buffers x (A 8192 + B 16384 shorts) = 144 KB.
// Swizzle (T2): logical [row][64 bf16] byte L at physical P = L ^ ((row&7)<<4).
// Staged via global_load_lds with linear dest + inverse-swizzled global source;
// ds_read side applies the swizzle -> conflict-free (verified: conflicts 20x down).
// Loads issued 2 K-tiles ahead; s_waitcnt vmcnt(6) per tile boundary (T4).
// SINGLE phase per K-tile: all 16 ds_read_b128 + all 6 gld_lds + 32 MFMA in
// one region, ONE barrier per K-tile (was 4). r2->r3 showed bigger MFMA
// clusters per barrier win at this geometry; intra-tile barriers are pacing
// only (reads target cb, stages target sb = kt-1 slot, retired last iter).
// MFMA operands SWAPPED (mfma(b,a)): acc rows = feats.
#define GLDA(j, bb, kt) gld16(Asrc[j] + (size_t)(kt) * 64, &smem[(bb) + ldsA + (j) * 4096])
#define GLDB(j, bb, kt) gld16(Bsrc[j] + (size_t)(kt) * 64, &smem[(bb) + 8192 + ldsA + (j) * 4096])

template <int EPI>
__global__ __launch_bounds__(512, 2) void gemm8p(
    const short* __restrict__ Ab, const short* __restrict__ Bt,
    const float* __restrict__ b0, const float* __restrict__ b1,
    const float* __restrict__ b2, float s0,
    short* __restrict__ outb) {
  __shared__ __align__(16) short smem[73728];   // 147456 B

  const int z = blockIdx.z;
  Ab += (size_t)z * 8388608;
  Bt += (size_t)z * 1048576;
  outb += (size_t)z * 8388608;
  const float* bias = z == 0 ? b0 : z == 1 ? b1 : b2;
  const float scale = z == 0 ? s0 : 1.f;

  const int tid = threadIdx.x;
  const int lane = tid & 63, w = tid >> 6;
  const int quad = lane >> 4, l16 = lane & 15;
  const int wm = (w >> 2) * 64, wn = (w & 3) * 64;   // 2M x 4N waves, 64x64 each
  const int mBase = blockIdx.x * 128, nBase = blockIdx.y * 256;

  f4v acc[4][4] = {};   // acc[nt][mt]: feat-frag nt, token-frag mt

  // staging: thread covers linear LDS slot s -> logical row s>>3,
  // logical col shorts ((s&7)^((s>>3)&7))<<3  (inverse swizzle on source)
  const short* Asrc[2];
  const short* Bsrc[4];
#pragma unroll
  for (int j = 0; j < 2; ++j) {
    int s = tid + j * 512;
    Asrc[j] = Ab + (size_t)(mBase + (s >> 3)) * 1024 + (((s & 7) ^ ((s >> 3) & 7)) << 3);
  }
#pragma unroll
  for (int j = 0; j < 4; ++j) {
    int s = tid + j * 512;
    Bsrc[j] = Bt + (size_t)(nBase + (s >> 3)) * 1024 + (((s & 7) ^ ((s >> 3) & 7)) << 3);
  }
  const int ldsA = tid * 8;

  // fragment read offsets (shorts within buf): row*64 + ((kh*4+quad)^(l16&7))<<3
  int axk[2];
#pragma unroll
  for (int kh = 0; kh < 2; ++kh) axk[kh] = (((kh * 4 + quad) ^ (l16 & 7)) << 3);
  const int arow = (wm + l16) * 64;          // + mt*1024
  const int brow = 8192 + (wn + l16) * 64;   // + nt*1024

  // ---- prologue: stage tiles 0,1,2 into bufs 0,1,2 (6 loads each) ----
#pragma unroll
  for (int t = 0; t < 3; ++t) {
    const int bb = t * 24576;
    GLDB(0, bb, t); GLDB(1, bb, t); GLDB(2, bb, t); GLDB(3, bb, t);
    GLDA(0, bb, t); GLDA(1, bb, t);
  }
  asm volatile("s_waitcnt vmcnt(12)" ::: "memory");   // tile 0 resident
  __builtin_amdgcn_s_barrier();

  int cb = 0, sb = 49152;   // current buf, stage buf (tile kt+2)
#pragma unroll 1
  for (int kt = 0; kt < 16; ++kt) {
    const bool st = (kt + 2) < 16;
    s8v a[4][2], b[4][2];
    // ---- all frags (16 ds_read_b128) + all stages (6 gld_lds) ----
#pragma unroll
    for (int kh = 0; kh < 2; ++kh) {
      b[0][kh] = *(const s8v*)&smem[cb + brow + 0 * 1024 + axk[kh]];
      b[1][kh] = *(const s8v*)&smem[cb + brow + 1 * 1024 + axk[kh]];
      b[2][kh] = *(const s8v*)&smem[cb + brow + 2 * 1024 + axk[kh]];
      b[3][kh] = *(const s8v*)&smem[cb + brow + 3 * 1024 + axk[kh]];
      a[0][kh] = *(const s8v*)&smem[cb + arow + 0 * 1024 + axk[kh]];
      a[1][kh] = *(const s8v*)&smem[cb + arow + 1 * 1024 + axk[kh]];
      a[2][kh] = *(const s8v*)&smem[cb + arow + 2 * 1024 + axk[kh]];
      a[3][kh] = *(const s8v*)&smem[cb + arow + 3 * 1024 + axk[kh]];
    }
    if (st) {
      GLDB(0, sb, kt + 2); GLDB(1, sb, kt + 2); GLDB(2, sb, kt + 2); GLDB(3, sb, kt + 2);
      GLDA(0, sb, kt + 2); GLDA(1, sb, kt + 2);
    }
    // ---- 32 MFMA; compiler interleaves lgkm waits with issue ----
    __builtin_amdgcn_s_setprio(1);
#pragma unroll
    for (int nt = 0; nt < 4; ++nt)
#pragma unroll
      for (int mt = 0; mt < 4; ++mt)
#pragma unroll
        for (int kh = 0; kh < 2; ++kh)
          acc[nt][mt] = MFMA16(b[nt][kh], a[mt][kh], acc[nt][mt]);
    __builtin_amdgcn_s_setprio(0);
    // ---- tile boundary: counted vmcnt (never 0 in steady state) ----
    if (kt < 14) {
      asm volatile("s_waitcnt vmcnt(6)" ::: "memory");   // next tile resident
    } else if (kt == 14) {
      asm volatile("s_waitcnt vmcnt(0)" ::: "memory");   // tail drain
    }
    if (kt < 15) __builtin_amdgcn_s_barrier();
    cb = (cb == 49152) ? 0 : cb + 24576;
    sb = (sb == 49152) ? 0 : sb + 24576;
  }

  // ---- epilogue: LDS transpose (pool is dead), coalesced 16B stores ----
  f4v bv_[4];
#pragma unroll
  for (int nt = 0; nt < 4; ++nt)
    bv_[nt] = *(const f4v*)&bias[nBase + wn + nt * 16 + quad * 4];

  const int bI = mBase >> 11, tok0 = mBase & 2047;
  const bool vpath = (EPI == 0) && (z == 2);
  if (vpath) {
    short (*Tv)[136] = (short(*)[136])smem;   // [feat 256][tok 128]
#pragma unroll
    for (int nt = 0; nt < 4; ++nt)
#pragma unroll
      for (int r = 0; r < 4; ++r) {
        int feat = wn + nt * 16 + quad * 4 + r;
#pragma unroll
        for (int mt = 0; mt < 4; ++mt)
          Tv[feat][wm + mt * 16 + l16] = f2bf(acc[nt][mt][r] + bv_[nt][r]);
      }
    __syncthreads();
#pragma unroll
    for (int it = 0; it < 8; ++it) {
      int id = tid + it * 512;
      int f = id >> 4, t8 = (id & 15) << 3;
      s8v v = *(const s8v*)&Tv[f][t8];
      int gf = nBase + f, h = gf >> 6, d = gf & 63;
      *(s8v*)&outb[(((size_t)bI * 16 + h) * 64 + d) * 2048 + tok0 + t8] = v;
    }
  } else {
    short (*Ta)[264] = (short(*)[264])smem;   // [tok 128][feat 256]
#pragma unroll
    for (int nt = 0; nt < 4; ++nt)
#pragma unroll
      for (int mt = 0; mt < 4; ++mt) {
        union { s4v v; unsigned u[2]; } pk;
        pk.u[0] = pack2rn((acc[nt][mt][1] + bv_[nt][1]) * scale,
                          (acc[nt][mt][0] + bv_[nt][0]) * scale);
        pk.u[1] = pack2rn((acc[nt][mt][3] + bv_[nt][3]) * scale,
                          (acc[nt][mt][2] + bv_[nt][2]) * scale);
        *(s4v*)&Ta[wm + mt * 16 + l16][wn + nt * 16 + quad * 4] = pk.v;
      }
    __syncthreads();
#pragma unroll
    for (int it = 0; it < 8; ++it) {
      int id = tid + it * 512;
      int tok = id >> 5, f8 = (id & 31) << 3;
      s8v v = *(const s8v*)&Ta[tok][f8];
      if constexpr (EPI == 1) {
        *(s8v*)&outb[(size_t)(mBase + tok) * 1024 + nBase + f8] = v;
      } else {
        int gf = nBase + f8, h = gf >> 6, d = gf & 63;
        *(s8v*)&outb[(((size_t)bI * 16 + h) * 2048 + tok0 + tok) * 64 + d] = v;
      }
    }
  }
}

// ---------- flash attention: S^T scheme, P in registers, dbuf K/V staging ----
// EXACT round-3 inner loop (measured 71.2/69.7 us) -- all structural variants
// (kv-split occupancy r6, SW-pipeline r7, issue-late T14 r8) measured worse.
// Loads for kv+1 issue at loop TOP; the barrier's implicit vmcnt(0) drain
// overlaps other waves' barrier arrival. No setprio (r3 form). FROZEN.
// T1 XCD swizzle: XCD x owns bh in [8x,8x+8) -> per-XCD K/V set = 4 MB = L2.
__global__ __launch_bounds__(256, 2) void attn_kernel(
    const short* __restrict__ Qp, const short* __restrict__ Kp,
    const short* __restrict__ Vpt, short* __restrict__ Ctx) {
  __shared__ __align__(16) short Ks[2][64][72];
  __shared__ __align__(16) short Vt[2][64][72];

  const int tid = threadIdx.x, w = tid >> 6, lane = tid & 63;
  const int quad = lane >> 4, l16 = lane & 15;
  const int lin = blockIdx.x + (blockIdx.y << 3);
  const int xcd = lin & 7, j = lin >> 3;
  const int bh = (xcd << 3) | (j >> 3), qt = j & 7;
  const short* Qb = Qp + (size_t)bh * 2048 * 64;
  const short* Kb = Kp + (size_t)bh * 2048 * 64;
  const short* Vb = Vpt + (size_t)bh * 64 * 2048;
  const int qbase = qt * 256 + w * 64;

  int sg[2], sc8[2], sp[2];
  const short* Ksrc[2];
  const short* Vsrc[2];
#pragma unroll
  for (int i = 0; i < 2; ++i) {
    int id = tid + i * 256;
    int g = id >> 3, c8 = (id & 7) << 3;
    int p = (g & 32) | (((g >> 2) & 1) << 4) | (((g >> 3) & 3) << 2) | (g & 3);
    sg[i] = g; sc8[i] = c8; sp[i] = p;
    Ksrc[i] = Kb + (size_t)g * 64 + c8;
    Vsrc[i] = Vb + (size_t)g * 2048 + c8;
  }

  s8v qf[4][2];
#pragma unroll
  for (int mt = 0; mt < 4; ++mt)
#pragma unroll
    for (int h = 0; h < 2; ++h)
      qf[mt][h] = *(const s8v*)(Qb + (size_t)(qbase + mt * 16 + l16) * 64 + h * 32 + quad * 8);

  {
    s8v kr[2], vr[2];
#pragma unroll
    for (int i = 0; i < 2; ++i) { kr[i] = *(const s8v*)Ksrc[i]; vr[i] = *(const s8v*)Vsrc[i]; }
#pragma unroll
    for (int i = 0; i < 2; ++i) {
      *(s8v*)&Ks[0][sp[i]][sc8[i]] = kr[i];
      *(s8v*)&Vt[0][sg[i]][sc8[i]] = vr[i];
    }
  }

  const s8v vone = {16256, 16256, 16256, 16256, 16256, 16256, 16256, 16256};
  f4v Oa[4][4] = {};
  f4v La[4] = {};

  for (int kv = 0; kv < 32; ++kv) {
    const int buf = kv & 1;
    s8v kn[2], vn[2];
    if (kv < 31) {
#pragma unroll
      for (int i = 0; i < 2; ++i) {
        kn[i] = *(const s8v*)(Ksrc[i] + (size_t)(kv + 1) * 4096);
        vn[i] = *(const s8v*)(Vsrc[i] + (size_t)(kv + 1) * 64);
      }
    }
    __syncthreads();   // buf's staging writes (prev iter) visible

    s8v kf[4][2], vf[4][2];
#pragma unroll
    for (int T = 0; T < 4; ++T) {
      kf[T][0] = *(const s8v*)&Ks[buf][T * 16 + l16][quad * 8];
      kf[T][1] = *(const s8v*)&Ks[buf][T * 16 + l16][32 + quad * 8];
      vf[T][0] = *(const s8v*)&Vt[buf][T * 16 + l16][quad * 8];
      vf[T][1] = *(const s8v*)&Vt[buf][T * 16 + l16][32 + quad * 8];
    }

#pragma unroll
    for (int mt = 0; mt < 4; ++mt) {
      f4v s[4] = {};
#pragma unroll
      for (int T = 0; T < 4; ++T) {
        s[T] = MFMA16(kf[T][0], qf[mt][0], s[T]);
        s[T] = MFMA16(kf[T][1], qf[mt][1], s[T]);
      }
#pragma unroll
      for (int T = 0; T < 4; ++T)
#pragma unroll
        for (int r = 0; r < 4; ++r)
          s[T][r] = __builtin_amdgcn_exp2f(s[T][r]);
      s8v pf[2];
#pragma unroll
      for (int cp = 0; cp < 2; ++cp) {
        union { s8v v; unsigned u[4]; } pk;
        pk.u[0] = pack2(s[2 * cp][1], s[2 * cp][0]);
        pk.u[1] = pack2(s[2 * cp][3], s[2 * cp][2]);
        pk.u[2] = pack2(s[2 * cp + 1][1], s[2 * cp + 1][0]);
        pk.u[3] = pack2(s[2 * cp + 1][3], s[2 * cp + 1][2]);
        pf[cp] = pk.v;
      }
      La[mt] = MFMA16(pf[0], vone, La[mt]);
      La[mt] = MFMA16(pf[1], vone, La[mt]);
#pragma unroll
      for (int nt = 0; nt < 4; ++nt) {
        Oa[mt][nt] = MFMA16(pf[0], vf[nt][0], Oa[mt][nt]);
        Oa[mt][nt] = MFMA16(pf[1], vf[nt][1], Oa[mt][nt]);
      }
    }

    if (kv < 31) {
#pragma unroll
      for (int i = 0; i < 2; ++i) {
        *(s8v*)&Ks[buf ^ 1][sp[i]][sc8[i]] = kn[i];
        *(s8v*)&Vt[buf ^ 1][sg[i]][sc8[i]] = vn[i];
      }
    }
  }

  const int b = bh >> 4, h = bh & 15;
#pragma unroll
  for (int mt = 0; mt < 4; ++mt)
#pragma unroll
    for (int r = 0; r < 4; ++r) {
      float inv = 1.f / La[mt][r];
      int q = qbase + mt * 16 + quad * 4 + r;
#pragma unroll
      for (int nt = 0; nt < 4; ++nt) {
        int d = nt * 16 + l16;
        Ctx[((size_t)b * 2048 + q) * 1024 + h * 64 + d] = f2bf(Oa[mt][nt][r] * inv);
      }
    }
}

// ---------- residual + LayerNorm (attn input in bf16) ----------
__global__ __launch_bounds__(256) void ln_kernel(
    const float* __restrict__ resid, const short* __restrict__ attnb,
    const float* __restrict__ gamma, const float* __restrict__ beta,
    float* __restrict__ out) {
  const int row = blockIdx.x, t = threadIdx.x;
  const float4 rv = *(const float4*)(resid + (size_t)row * 1024 + t * 4);
  const s4v av = *(const s4v*)(attnb + (size_t)row * 1024 + t * 4);
  float x0 = rv.x + bf2f(av[0]), x1 = rv.y + bf2f(av[1]);
  float x2 = rv.z + bf2f(av[2]), x3 = rv.w + bf2f(av[3]);
  float s = x0 + x1 + x2 + x3;
  float ss = x0 * x0 + x1 * x1 + x2 * x2 + x3 * x3;
  for (int off = 32; off > 0; off >>= 1) {
    s += __shfl_down(s, off, 64);
    ss += __shfl_down(ss, off, 64);
  }
  __shared__ float red[8];
  const int wid = t >> 6, lane = t & 63;
  if (lane == 0) { red[wid] = s; red[4 + wid] = ss; }
  __syncthreads();
  float S = red[0] + red[1] + red[2] + red[3];
  float SS = red[4] + red[5] + red[6] + red[7];
  float mu = S * (1.f / 1024.f);
  float var = SS * (1.f / 1024.f) - mu * mu;
  float rstd = rsqrtf(var + 1e-5f);
  const float4 g = *(const float4*)(gamma + t * 4);
  const float4 bb = *(const float4*)(beta + t * 4);
  float4 o;
  o.x = (x0 - mu) * rstd * g.x + bb.x;
  o.y = (x1 - mu) * rstd * g.y + bb.y;
  o.z = (x2 - mu) * rstd * g.z + bb.z;
  o.w = (x3 - mu) * rstd * g.w + bb.w;
  *(float4*)(out + (size_t)row * 1024 + t * 4) = o;
}

extern "C" void kernel_launch(void* const* d_in, const int* in_sizes, int n_in,
                              void* d_out, int out_size, void* d_ws, size_t ws_size,
                              hipStream_t stream) {
  const float* Qin = (const float*)d_in[0];
  const float* Kin = (const float*)d_in[1];
  const float* Vin = (const float*)d_in[2];
  const float* Wq = (const float*)d_in[3];
  const float* bq = (const float*)d_in[4];
  const float* Wk = (const float*)d_in[5];
  const float* bk = (const float*)d_in[6];
  const float* Wv = (const float*)d_in[7];
  const float* bv = (const float*)d_in[8];
  const float* Wo = (const float*)d_in[9];
  const float* bo = (const float*)d_in[10];
  const float* gamma = (const float*)d_in[11];
  const float* beta = (const float*)d_in[12];
  float* out = (float*)d_out;

  char* ws = (char*)d_ws;
  const size_t MB = 1024 * 1024;
  // Layout (peak 104 MB):
  //  [0,48M)   Qp/Kp/Vpt  (QKV gemm out; live through attn)
  //  [48,96M)  Acast      (bf16 inputs; dead after QKV gemm)  -> reused:
  //  [48,64M)  Ctx        (attn out)
  //  [64,80M)  AOutB      (O-proj out)
  //  [96,104M) Wt         (4 x 2MB transposed weights)
  short* Qp    = (short*)(ws);
  short* Acast = (short*)(ws + 48 * MB);
  short* Ctx   = (short*)(ws + 48 * MB);
  short* AOutB = (short*)(ws + 64 * MB);
  short* Wt    = (short*)(ws + 96 * MB);

  prep<<<7168, 256, 0, stream>>>(Wq, Wk, Wv, Wo, Wt, Qin, Kin, Vin, Acast);

  const float qscale = 0.125f * 1.44269504f;  // 1/sqrt(64) * log2(e)

  gemm8p<0><<<dim3(64, 4, 3), 512, 0, stream>>>(
      Acast, Wt, bq, bk, bv, qscale, Qp);

  attn_kernel<<<dim3(8, 64), 256, 0, stream>>>(Qp, Qp + 8388608, Qp + 16777216, Ctx);

  gemm8p<1><<<dim3(64, 4, 1), 512, 0, stream>>>(
      Ctx, Wt + 3 * 1048576, bo, bo, bo, 1.f, AOutB);

  ln_kernel<<<8192, 256, 0, stream>>>(Qin, AOutB, gamma, beta, out);
}